// Round 12
// baseline (978.982 us; speedup 1.0000x reference)
//
#include <hip/hip_runtime.h>
#include <hip/hip_bf16.h>
#include <math.h>

// Problem constants
#define TT   128
#define BB   256
#define DIN  256
#define DH   1024
#define DOUT 256

// R11-proven core: 8 row-groups x 32 col-blocks, 128 thr, H in MFMA B-fragment
// order (coalesced exchange), flagless epoch-bit sync (every 8B word carries
// code(t)=1+((t-1)%15) in its 4 halfword LSBs; written by one AGST; consumers
// validate and AGLD-retry on mismatch). absmax-verified at 0.0625.
//
// R12: serve the 32-way fan-out from the XCD L2 instead of the MALL.
//  - consumers' FIRST pass = plain cached 16B loads on a 63-version ring:
//    virgin addresses -> L2 miss -> one fill/line from MALL -> remaining
//    same-XCD blocks hit L2 (34 TB/s) instead of MALL (~2.9 TB/s observed).
//  - producers stay AGST (write-through to MALL, proven): any consumer fill
//    ordered after the AGST sees fresh data; any race/stale line fails the
//    epoch check and is re-read via AGLD (proven). No ordering assumptions,
//    no fences, no flags: correctness is purely value-based.
//  - ring reuse after 63 steps: 63%15=3, 126%15=6 -> stale codes never alias.
//  - all 4 chunks prefetched upfront (128 VGPR buffers; fits 2 blocks/CU).
// ws too small for the ring -> exact R11 fallback (M=2, AGLD-only).
#define NGM 8
#define MR  32
#define NGN 32
#define NC  32

typedef float  floatx4 __attribute__((ext_vector_type(4)));
typedef short  shortx8 __attribute__((ext_vector_type(8)));
typedef unsigned long long u64;

#define CMASK 0x0001000100010001ULL
#define GSTRIDE 32768           // shorts per group slab (2*32*4*16*8)

__device__ __forceinline__ short f2bf(float f) {
    union { float f; unsigned u; } v; v.f = f;
    unsigned r = v.u + 0x7fffu + ((v.u >> 16) & 1u);   // RNE, inputs never NaN
    return (short)(r >> 16);
}

// RNE to the bf16 grid restricted to LSB==bit (step 2 ulp): err <= 1 ulp bf16
__device__ __forceinline__ unsigned short bf15e(float v, unsigned bit) {
    union { float f; unsigned u; } x; x.f = v;
    unsigned ua = x.u - (bit << 16);
    unsigned k  = (ua + 0xFFFFu + ((ua >> 17) & 1u)) >> 17;
    return (unsigned short)((k << 1) | bit);
}

__device__ __forceinline__ shortx8 mk8(u64 lo, u64 hi) {
    union { struct { u64 a, b; } s; shortx8 v; } u;
    u.s.a = lo; u.s.b = hi;
    return u.v;
}

__device__ __forceinline__ float fast_tanh(float z) {
    float e = __expf(2.0f * fabsf(z));
    float r = 1.0f - 2.0f / (e + 1.0f);
    return copysignf(r, z);
}

#define AGLD(p)    __hip_atomic_load((p),  __ATOMIC_RELAXED, __HIP_MEMORY_SCOPE_AGENT)
#define AGST(p, v) __hip_atomic_store((p), (v), __ATOMIC_RELAXED, __HIP_MEMORY_SCOPE_AGENT)

// AGLD chunk load (retry path + small-path first pass); coalesced across lanes
#define LD16(buf, base) do { \
    _Pragma("unroll") \
    for (int _j = 0; _j < 8; ++_j) { \
        const u64* _p = (const u64*)(hfr + ((base) + _j) * 512); \
        buf[2 * _j]     = AGLD(_p); \
        buf[2 * _j + 1] = AGLD(_p + 1); \
    } } while (0)
// plain cached 16B first pass (big path: virgin ring addresses -> L2 fill)
#define LD16P(buf, base) do { \
    _Pragma("unroll") \
    for (int _j = 0; _j < 8; ++_j) { \
        union { shortx8 s; u64 d[2]; } _u; \
        _u.s = *(const shortx8*)(hfr + ((base) + _j) * 512); \
        buf[2 * _j] = _u.d[0]; buf[2 * _j + 1] = _u.d[1]; \
    } } while (0)
#define OK16(buf, okvar) do { \
    int _o = 1; \
    _Pragma("unroll") \
    for (int _j = 0; _j < 16; ++_j) _o &= ((buf[_j] & CMASK) == pat); \
    okvar = __all(_o); } while (0)
#define WAITVALID(buf, base) do { \
    int _okk; OK16(buf, _okk); \
    while (!_okk) { __builtin_amdgcn_s_sleep(1); LD16(buf, base); OK16(buf, _okk); } \
    } while (0)
#define CONS16(buf, base) do { \
    _Pragma("unroll") \
    for (int _j = 0; _j < 8; ++_j) { \
        shortx8 bfr = mk8(buf[2 * _j], buf[2 * _j + 1]); \
        shortx8 a0 = *(const shortx8*)&WhL[(base) + _j][0][q][lr][0]; \
        shortx8 a1 = *(const shortx8*)&WhL[(base) + _j][1][q][lr][0]; \
        acc0 = __builtin_amdgcn_mfma_f32_16x16x32_bf16(a0, bfr, acc0, 0, 0, 0); \
        acc1 = __builtin_amdgcn_mfma_f32_16x16x32_bf16(a1, bfr, acc1, 0, 0, 0); \
    } } while (0)

__global__ __launch_bounds__(128, 1) void rnn_steps_kernel(
    const float* __restrict__ xs, const float* __restrict__ W1x,
    const float* __restrict__ W1h, const float* __restrict__ b1,
    short* __restrict__ Hbuf, int big, int M)
{
    const int gm  = blockIdx.x;   // 0..7 row group
    const int gn  = blockIdx.y;   // 0..31 col block
    const int tid = threadIdx.x;
    const int w   = tid >> 6;     // wave -> 16-row tile
    const int l   = tid & 63;
    const int lr  = l & 15;
    const int q   = l >> 4;       // MFMA k-quad

    const int r0 = gm * MR;
    const int c0 = gn * NC;

    // W1h slice as MFMA A-fragments in LDS (R3-proven layout)
    __shared__ short WhL[DH / 32][2][4][16][8];   // 64 KB
    for (int idx = tid; idx < (DH / 32) * 2 * 4 * 16; idx += 128) {
        const int c  = idx & 15;
        const int qq = (idx >> 4) & 3;
        const int ct = (idx >> 6) & 1;
        const int ks = idx >> 7;
        shortx8 f;
        #pragma unroll
        for (int j = 0; j < 8; ++j)
            f[j] = f2bf(W1h[(size_t)(ks * 32 + qq * 8 + j) * DH + c0 + ct * 16 + c]);
        *(shortx8*)&WhL[ks][ct][qq][c][0] = f;
    }
    // W1x A-fragments register-resident (32 VGPRs)
    shortx8 wx[2][8];
    #pragma unroll
    for (int ct = 0; ct < 2; ++ct)
        #pragma unroll
        for (int ks = 0; ks < 8; ++ks) {
            shortx8 f;
            #pragma unroll
            for (int j = 0; j < 8; ++j)
                f[j] = f2bf(W1x[(size_t)(ks * 32 + q * 8 + j) * DH + c0 + ct * 16 + lr]);
            wx[ct][ks] = f;
        }
    __syncthreads();   // WhL ready; no barriers after this point

    floatx4 bias[2];
    #pragma unroll
    for (int ct = 0; ct < 2; ++ct)
        #pragma unroll
        for (int r = 0; r < 4; ++r) bias[ct][r] = b1[c0 + ct * 16 + q * 4 + r];

    const int myrow = r0 + w * 16 + lr;        // xs rows
    const size_t HS = (size_t)BB * DH;         // shorts per version

    short* const Hg = Hbuf + gm * GSTRIDE;
    const int rdoff = w * 16384 + q * 128 + lr * 8;
    const int wroff = w * 16384 + gn * 512 + (q >> 1) * 128 + lr * 8 + (q & 1) * 4;

    int cv = 1 % M, pv = 0;      // version ring: v(t)=t%M (M=2 -> parity)

    for (int t = 1; t <= TT; ++t) {
        const short* const hfr = Hg + (size_t)pv * HS + rdoff;
        const int pc = (t >= 2) ? (1 + ((t - 2) % 15)) : 0;
        const u64 pat = ((u64)(pc & 1)) | ((u64)((pc >> 1) & 1) << 16) |
                        ((u64)((pc >> 2) & 1) << 32) | ((u64)((pc >> 3) & 1) << 48);

        u64 A[16], B[16], C[16], D[16];
        if (t > 1) {
            if (big) {           // prefetch all 4 chunks, plain cached (L2 path)
                LD16P(A, 0); LD16P(B, 8); LD16P(C, 16); LD16P(D, 24);
            } else {
                LD16(A, 0);      // R11: early AGLD prefetch of chunk 0
            }
        }

        floatx4 acc0 = {0.f, 0.f, 0.f, 0.f}, acc1 = {0.f, 0.f, 0.f, 0.f};

        // ---- x_t @ W1x: independent of h, hides fill/propagate latency ----
        {
            const float* xrow = xs + ((size_t)(t - 1) * BB + myrow) * DIN + q * 8;
            #pragma unroll
            for (int ks = 0; ks < 8; ++ks) {
                floatx4 x0 = *(const floatx4*)(xrow + ks * 32);
                floatx4 x1 = *(const floatx4*)(xrow + ks * 32 + 4);
                shortx8 b;
                b[0] = f2bf(x0[0]); b[1] = f2bf(x0[1]); b[2] = f2bf(x0[2]); b[3] = f2bf(x0[3]);
                b[4] = f2bf(x1[0]); b[5] = f2bf(x1[1]); b[6] = f2bf(x1[2]); b[7] = f2bf(x1[3]);
                acc0 = __builtin_amdgcn_mfma_f32_16x16x32_bf16(wx[0][ks], b, acc0, 0, 0, 0);
                acc1 = __builtin_amdgcn_mfma_f32_16x16x32_bf16(wx[1][ks], b, acc1, 0, 0, 0);
            }
        }

        // ---- h_{t-1} @ W1h: validate-and-retry chunk pipeline ----
        if (t > 1) {
            if (big) {
                WAITVALID(A, 0);  CONS16(A, 0);
                WAITVALID(B, 8);  CONS16(B, 8);
                WAITVALID(C, 16); CONS16(C, 16);
                WAITVALID(D, 24); CONS16(D, 24);
            } else {
                LD16(B, 8);
                WAITVALID(A, 0);  CONS16(A, 0);
                LD16(C, 16);
                WAITVALID(B, 8);  CONS16(B, 8);
                LD16(D, 24);
                WAITVALID(C, 16); CONS16(C, 16);
                WAITVALID(D, 24); CONS16(D, 24);
            }
        }

        // ---- tanh, encode epoch bits, two 8B coalesced AGSTs ----
        {
            const int cc = 1 + ((t - 1) % 15);     // code(t), never 0 (=poison)
            short* hp = Hg + (size_t)cv * HS + wroff;
            u64 p0 = 0, p1 = 0;
            #pragma unroll
            for (int r = 0; r < 4; ++r) {
                const unsigned bit = ((unsigned)cc >> r) & 1u;
                p0 |= ((u64)bf15e(fast_tanh(acc0[r] + bias[0][r]), bit)) << (16 * r);
                p1 |= ((u64)bf15e(fast_tanh(acc1[r] + bias[1][r]), bit)) << (16 * r);
            }
            AGST((u64*)(hp), p0);            // ct=0
            AGST((u64*)(hp + 256), p1);      // ct=1
            // fire-and-forget: words self-validate at consumers
        }

        pv = cv; cv = (cv + 1 == M) ? 0 : cv + 1;
    }
}

// out[b][o] = sum_k h[b][k]*W2[k][o] + b2. Final h is in fragment layout;
// decode while staging via AGLD into LDS (AGLD: fresh vs any stale L2 lines).
__global__ __launch_bounds__(256) void readout_kernel(
    const short* __restrict__ Hfin, const float* __restrict__ W2,
    const float* __restrict__ b2, float* __restrict__ out)
{
    const int o  = threadIdx.x;
    const int b0 = blockIdx.x * 4;
    __shared__ u64 hs8[4 * DH / 4];            // [row][col/4], 8 KB
    for (int ch = o; ch < 4 * DH / 4; ch += 256) {
        const int row  = ch >> 8;              // 0..3
        const int col0 = (ch & 255) * 4;       // 0,4,..,1020
        const int rr   = b0 + row;
        const int gmr  = rr >> 5, rt = (rr >> 4) & 1, lrr = rr & 15;
        const int ks   = col0 >> 5, qq = (col0 >> 3) & 3, j0 = col0 & 7;
        const u64* src = (const u64*)(Hfin + (size_t)gmr * GSTRIDE + rt * 16384 +
                                      ks * 512 + qq * 128 + lrr * 8 + j0);
        hs8[ch] = AGLD(src);
    }
    __syncthreads();
    const unsigned* h0 = (const unsigned*)&hs8[0 * 256];
    const unsigned* h1 = (const unsigned*)&hs8[1 * 256];
    const unsigned* h2 = (const unsigned*)&hs8[2 * 256];
    const unsigned* h3 = (const unsigned*)&hs8[3 * 256];
    float a0 = 0.f, a1 = 0.f, a2 = 0.f, a3 = 0.f;
    for (int k2 = 0; k2 < DH / 2; ++k2) {
        float w0 = W2[(2 * k2)     * DOUT + o];
        float w1 = W2[(2 * k2 + 1) * DOUT + o];
        unsigned p0 = h0[k2], p1 = h1[k2], p2 = h2[k2], p3 = h3[k2];
        a0 += __builtin_bit_cast(float, p0 << 16) * w0 + __builtin_bit_cast(float, p0 & 0xffff0000u) * w1;
        a1 += __builtin_bit_cast(float, p1 << 16) * w0 + __builtin_bit_cast(float, p1 & 0xffff0000u) * w1;
        a2 += __builtin_bit_cast(float, p2 << 16) * w0 + __builtin_bit_cast(float, p2 & 0xffff0000u) * w1;
        a3 += __builtin_bit_cast(float, p3 << 16) * w0 + __builtin_bit_cast(float, p3 & 0xffff0000u) * w1;
    }
    const float bias = b2[0];
    out[(b0 + 0) * DOUT + o] = a0 + bias;
    out[(b0 + 1) * DOUT + o] = a1 + bias;
    out[(b0 + 2) * DOUT + o] = a2 + bias;
    out[(b0 + 3) * DOUT + o] = a3 + bias;
}

extern "C" void kernel_launch(void* const* d_in, const int* in_sizes, int n_in,
                              void* d_out, int out_size, void* d_ws, size_t ws_size,
                              hipStream_t stream) {
    (void)in_sizes; (void)n_in; (void)out_size;
    const float* xs  = (const float*)d_in[0];   // [128,256,256]
    const float* W1x = (const float*)d_in[1];   // [256,1024]
    const float* W1h = (const float*)d_in[2];   // [1024,1024]
    const float* b1  = (const float*)d_in[3];   // [1024]
    const float* W2  = (const float*)d_in[4];   // [1024,256]
    const float* b2  = (const float*)d_in[5];   // scalar
    float* out = (float*)d_out;                 // [256,256]

    // big: 63-version ring (31.5 MB), fragment layout. small: R11 parity (1MB).
    // No flags, no memset: 0xAA poison -> code 0, never matches codes 1..15.
    const size_t HS = (size_t)BB * DH;          // shorts per version
    int M = 63, big = 1;
    if (ws_size < (size_t)63 * HS * sizeof(short) + 1024) { big = 0; M = 2; }
    short* Hbuf = (short*)d_ws;

    rnn_steps_kernel<<<dim3(NGM, NGN), 128, 0, stream>>>(
        xs, W1x, W1h, b1, Hbuf, big, M);
    const short* Hfin = Hbuf + (size_t)(TT % M) * HS;    // h_128
    readout_kernel<<<dim3(BB / 4), 256, 0, stream>>>(Hfin, W2, b2, out);
}